// Round 2
// baseline (4997.685 us; speedup 1.0000x reference)
//
#include <hip/hip_runtime.h>
#include <math.h>

// Problem constants (from reference): H1=15, H2=60, H3=20, T=15, IN=1
#define HH   15          // LSTM hidden size (both layers)
#define HP   16          // padded hidden (row stride, aligned ds_read_b128)
#define G4   60          // 4*HH gate rows
#define TT   15          // time steps
#define NH2  60          // head layer 1 width
#define NH3  20          // head layer 2 width

__device__ __forceinline__ float fast_rcp(float x) {
    return __builtin_amdgcn_rcpf(x);   // v_rcp_f32, ~1 ulp
}
__device__ __forceinline__ float sigm(float x) {
    // 1/(1+exp(-x)); exp(-x)->inf => rcp(inf)=0 => 0 (correct), no NaN
    return fast_rcp(1.0f + __expf(-x));
}
__device__ __forceinline__ float tanhx(float x) {
    // tanh(x) = 1 - 2/(1+exp(2x)); exp->inf => rcp->0 => 1; exp->0 => -1. NaN-safe.
    float e = __expf(2.0f * x);
    return 1.0f - 2.0f * fast_rcp(1.0f + e);
}

// One thread per batch element; all LSTM state in registers.
// amdgpu_waves_per_eu(2,2): grid gives only 2 waves/SIMD anyway (2048 waves /
// 1024 SIMDs), so pin the regalloc target to 2 waves/EU => full 256-VGPR
// budget => no scratch spill (round 1: compiler targeted 128 VGPRs and
// spilled ~12.7 GB of scratch traffic, 96% of runtime).
__global__ __launch_bounds__(256)
__attribute__((amdgpu_waves_per_eu(2, 2)))
void lstm_fused(const float* __restrict__ x,
                const float* __restrict__ Wih0, const float* __restrict__ Whh0,
                const float* __restrict__ bih0, const float* __restrict__ bhh0,
                const float* __restrict__ Wih1, const float* __restrict__ Whh1,
                const float* __restrict__ bih1, const float* __restrict__ bhh1,
                const float* __restrict__ W1, const float* __restrict__ b1,
                const float* __restrict__ W2, const float* __restrict__ b2,
                const float* __restrict__ W3, const float* __restrict__ b3,
                float* __restrict__ out, int B)
{
    // Weight rows padded to 16 floats (64 B) so each gate-row read is
    // 4 aligned ds_read_b128 wave-uniform broadcasts (conflict-free).
    __shared__ float sWih0[G4];        // (60,1)
    __shared__ float sB0[G4];          // bih0+bhh0
    __shared__ float sB1[G4];          // bih1+bhh1
    __shared__ float sW0[G4 * HP];     // Whh0 padded (60,16)
    __shared__ float sW1i[G4 * HP];    // Wih1 padded (60,16)
    __shared__ float sW1h[G4 * HP];    // Whh1 padded (60,16)
    __shared__ float sV[TT];           // collapsed head vector
    __shared__ float sU[NH2];          // temp: W3 @ W2
    __shared__ float sCb;              // collapsed head bias

    const int tid = threadIdx.x;

    // ---- stage weights into LDS ----
    for (int i = tid; i < G4; i += 256) {
        sWih0[i] = Wih0[i];
        sB0[i]   = bih0[i] + bhh0[i];
        sB1[i]   = bih1[i] + bhh1[i];
    }
    for (int i = tid; i < G4 * HP; i += 256) {
        const int r = i >> 4, k = i & 15;
        const bool valid = (k < HH);
        sW0[i]  = valid ? Whh0[r * HH + k] : 0.0f;
        sW1i[i] = valid ? Wih1[r * HH + k] : 0.0f;
        sW1h[i] = valid ? Whh1[r * HH + k] : 0.0f;
    }
    // ---- collapse the affine head: u = W3@W2 (60), v = u@W1 (15), c scalar ----
    if (tid < NH2) {
        float u = 0.0f;
        #pragma unroll
        for (int k = 0; k < NH3; ++k) u = fmaf(W3[k], W2[k * NH2 + tid], u);
        sU[tid] = u;
    }
    __syncthreads();
    if (tid < TT) {
        float v = 0.0f;
        for (int j = 0; j < NH2; ++j) v = fmaf(sU[j], W1[j * HH + tid], v);
        sV[tid] = v;
    }
    if (tid == 0) {
        float c = b3[0];
        for (int k = 0; k < NH3; ++k) c = fmaf(W3[k], b2[k], c);
        for (int j = 0; j < NH2; ++j) c = fmaf(sU[j], b1[j], c);
        sCb = c;
    }
    __syncthreads();

    const int b = blockIdx.x * 256 + tid;
    if (b >= B) return;

    const float* xp = x + (size_t)b * TT;

    // per-element LSTM state, all registers; h vectors padded to 16 with a
    // zero in [15] so the 16-wide dot against padded weight rows is exact.
    float h1[HP], c1[HH], h2[HP], c2[HH];
    #pragma unroll
    for (int u = 0; u < HH; ++u) { h1[u] = 0.0f; c1[u] = 0.0f; h2[u] = 0.0f; c2[u] = 0.0f; }
    h1[HH] = 0.0f; h2[HH] = 0.0f;

    float acc = sCb;

    #pragma unroll 1   // keep code size ~1 step (inside L1I); 15x unroll would be ~380 KB
    for (int t = 0; t < TT; ++t) {
        const float xt = xp[t];

        // ---------- layer 1 ----------
        float h1n[HP];
        h1n[HH] = 0.0f;
        #pragma unroll
        for (int u = 0; u < HH; ++u) {
            float ig = fmaf(sWih0[u],          xt, sB0[u]);
            float fg = fmaf(sWih0[HH + u],     xt, sB0[HH + u]);
            float gg = fmaf(sWih0[2 * HH + u], xt, sB0[2 * HH + u]);
            float og = fmaf(sWih0[3 * HH + u], xt, sB0[3 * HH + u]);
            #pragma unroll
            for (int k = 0; k < HP; ++k) {
                const float hk = h1[k];
                ig = fmaf(sW0[(u)          * HP + k], hk, ig);
                fg = fmaf(sW0[(HH + u)     * HP + k], hk, fg);
                gg = fmaf(sW0[(2 * HH + u) * HP + k], hk, gg);
                og = fmaf(sW0[(3 * HH + u) * HP + k], hk, og);
            }
            const float cc = sigm(fg) * c1[u] + sigm(ig) * tanhx(gg);
            c1[u] = cc;
            h1n[u] = sigm(og) * tanhx(cc);
        }

        // ---------- layer 2 (input = h1n) ----------
        float h2n[HH];
        #pragma unroll
        for (int u = 0; u < HH; ++u) {
            float ig = sB1[u];
            float fg = sB1[HH + u];
            float gg = sB1[2 * HH + u];
            float og = sB1[3 * HH + u];
            #pragma unroll
            for (int k = 0; k < HP; ++k) {
                const float hk = h1n[k];
                ig = fmaf(sW1i[(u)          * HP + k], hk, ig);
                fg = fmaf(sW1i[(HH + u)     * HP + k], hk, fg);
                gg = fmaf(sW1i[(2 * HH + u) * HP + k], hk, gg);
                og = fmaf(sW1i[(3 * HH + u) * HP + k], hk, og);
            }
            #pragma unroll
            for (int k = 0; k < HP; ++k) {
                const float hk = h2[k];
                ig = fmaf(sW1h[(u)          * HP + k], hk, ig);
                fg = fmaf(sW1h[(HH + u)     * HP + k], hk, fg);
                gg = fmaf(sW1h[(2 * HH + u) * HP + k], hk, gg);
                og = fmaf(sW1h[(3 * HH + u) * HP + k], hk, og);
            }
            const float cc = sigm(fg) * c2[u] + sigm(ig) * tanhx(gg);
            c2[u] = cc;
            h2n[u] = sigm(og) * tanhx(cc);
        }

        #pragma unroll
        for (int k = 0; k < HH; ++k) { h1[k] = h1n[k]; h2[k] = h2n[k]; }

        // feat[b,t] = h2_t[14]; accumulate collapsed head online
        acc = fmaf(h2n[HH - 1], sV[t], acc);
    }

    out[b] = acc;
}

extern "C" void kernel_launch(void* const* d_in, const int* in_sizes, int n_in,
                              void* d_out, int out_size, void* d_ws, size_t ws_size,
                              hipStream_t stream) {
    (void)n_in; (void)d_ws; (void)ws_size; (void)out_size;
    const float* x    = (const float*)d_in[0];
    const float* Wih0 = (const float*)d_in[1];
    const float* Whh0 = (const float*)d_in[2];
    const float* bih0 = (const float*)d_in[3];
    const float* bhh0 = (const float*)d_in[4];
    const float* Wih1 = (const float*)d_in[5];
    const float* Whh1 = (const float*)d_in[6];
    const float* bih1 = (const float*)d_in[7];
    const float* bhh1 = (const float*)d_in[8];
    const float* W1   = (const float*)d_in[9];
    const float* b1   = (const float*)d_in[10];
    const float* W2   = (const float*)d_in[11];
    const float* b2   = (const float*)d_in[12];
    const float* W3   = (const float*)d_in[13];
    const float* b3   = (const float*)d_in[14];
    float* out = (float*)d_out;

    const int B = in_sizes[0] / TT;   // 131072
    const int block = 256;
    const int grid = (B + block - 1) / block;

    lstm_fused<<<grid, block, 0, stream>>>(x, Wih0, Whh0, bih0, bhh0,
                                           Wih1, Whh1, bih1, bhh1,
                                           W1, b1, W2, b2, W3, b3, out, B);
}

// Round 4
// 4885.812 us; speedup vs baseline: 1.0229x; 1.0229x over previous
//
#include <hip/hip_runtime.h>

// Problem constants (from reference): H1=15, H2=60, H3=20, T=15, IN=1
#define HH   15          // LSTM hidden size (both layers)
#define HP   16          // padded hidden (row stride, 64 B rows)
#define G4   60          // 4*HH gate rows
#define TT   15          // time steps
#define NH2  60          // head layer 1 width
#define NH3  20          // head layer 2 width

#define LOG2E 1.44269504088896340736f

// First-class vector types: SSA values in IR, never allocas -> never scratch
// (round 2 post-mortem: float arrays stayed in scratch, 12.7 GB HBM traffic).
typedef float vf16 __attribute__((ext_vector_type(16)));
typedef float vf4  __attribute__((ext_vector_type(4)));

__device__ __forceinline__ float fast_rcp(float x) {
    return __builtin_amdgcn_rcpf(x);   // v_rcp_f32, ~1 ulp
}
__device__ __forceinline__ float fast_exp2(float x) {
    return __builtin_amdgcn_exp2f(x);  // v_exp_f32 (2^x). NOT __exp2f: glibc macro collision.
}
// Inputs pre-scaled by LOG2E (i,f,o gates) or 2*LOG2E (g gate) at staging.
// NaN-safe: exp2->inf => rcp->0.
__device__ __forceinline__ float sigm2(float y) {   // sigmoid(x), y = LOG2E*x
    return fast_rcp(1.0f + fast_exp2(-y));
}
__device__ __forceinline__ float tanh2(float y) {   // tanh(x), y = 2*LOG2E*x
    return 1.0f - 2.0f * fast_rcp(1.0f + fast_exp2(y));
}

// One thread per batch element; all LSTM state in ext-vector registers.
// Grid gives 2 waves/SIMD (2048 waves / 1024 SIMDs); pin regalloc to that.
__global__ __launch_bounds__(256, 2)
__attribute__((amdgpu_waves_per_eu(2, 2)))
void lstm_fused(const float* __restrict__ x,
                const float* __restrict__ Wih0, const float* __restrict__ Whh0,
                const float* __restrict__ bih0, const float* __restrict__ bhh0,
                const float* __restrict__ Wih1, const float* __restrict__ Whh1,
                const float* __restrict__ bih1, const float* __restrict__ bhh1,
                const float* __restrict__ W1, const float* __restrict__ b1,
                const float* __restrict__ W2, const float* __restrict__ b2,
                const float* __restrict__ W3, const float* __restrict__ b3,
                float* __restrict__ out, int B)
{
    // Weight rows padded to 16 floats (4 x vf4); all reads are wave-uniform
    // broadcasts (conflict-free ds_read_b128).
    __shared__ vf4  sW0 [G4 * 4];      // Whh0, gate-scaled
    __shared__ vf4  sW1i[G4 * 4];      // Wih1, gate-scaled
    __shared__ vf4  sW1h[G4 * 4];      // Whh1, gate-scaled
    __shared__ float sWx0[G4];         // Wih0 (60,1), gate-scaled
    __shared__ float sB0[G4];          // (bih0+bhh0), gate-scaled
    __shared__ float sB1[G4];          // (bih1+bhh1), gate-scaled
    __shared__ float sV[TT];           // collapsed head vector
    __shared__ float sU[NH2];          // temp: W3 @ W2
    __shared__ float sCb;              // collapsed head bias

    const int tid = threadIdx.x;

    // ---- stage weights into LDS, folding LOG2E into gate pre-activations ----
    // gate rows: i=[0,15) f=[15,30) g=[30,45) o=[45,60); g rows get 2*LOG2E.
    for (int i = tid; i < G4; i += 256) {
        const float sc = (i >= 2 * HH && i < 3 * HH) ? (2.0f * LOG2E) : LOG2E;
        sWx0[i] = Wih0[i] * sc;
        sB0[i]  = (bih0[i] + bhh0[i]) * sc;
        sB1[i]  = (bih1[i] + bhh1[i]) * sc;
    }
    for (int i = tid; i < G4 * HP; i += 256) {
        const int r = i >> 4, k = i & 15;
        const float sc = (r >= 2 * HH && r < 3 * HH) ? (2.0f * LOG2E) : LOG2E;
        const bool valid = (k < HH);
        ((float*)sW0)[i]  = valid ? Whh0[r * HH + k] * sc : 0.0f;
        ((float*)sW1i)[i] = valid ? Wih1[r * HH + k] * sc : 0.0f;
        ((float*)sW1h)[i] = valid ? Whh1[r * HH + k] * sc : 0.0f;
    }
    // ---- collapse the affine head: u = W3@W2 (60), v = u@W1 (15), c scalar ----
    if (tid < NH2) {
        float u = 0.0f;
        #pragma unroll
        for (int k = 0; k < NH3; ++k) u = fmaf(W3[k], W2[k * NH2 + tid], u);
        sU[tid] = u;
    }
    __syncthreads();
    if (tid < TT) {
        float v = 0.0f;
        for (int j = 0; j < NH2; ++j) v = fmaf(sU[j], W1[j * HH + tid], v);
        sV[tid] = v;
    }
    if (tid == 0) {
        float c = b3[0];
        for (int k = 0; k < NH3; ++k) c = fmaf(W3[k], b2[k], c);
        for (int j = 0; j < NH2; ++j) c = fmaf(sU[j], b1[j], c);
        sCb = c;
    }
    __syncthreads();

    const int b = blockIdx.x * 256 + tid;
    if (b >= B) return;

    const float* xp = x + (size_t)b * TT;

    // state vectors; element 15 stays 0.0 (dotted against zero-padded rows)
    vf16 h1, c1, h2, c2;
    #pragma unroll
    for (int k = 0; k < 16; ++k) { h1[k] = 0.0f; c1[k] = 0.0f; h2[k] = 0.0f; c2[k] = 0.0f; }

    float acc = sCb;

    #pragma unroll 1   // one step of code; 15x unroll would blow L1I
    for (int t = 0; t < TT; ++t) {
        const float xt = xp[t];

        // ---------- layer 1 ----------
        vf16 h1n;
        h1n[15] = 0.0f;
        #pragma unroll
        for (int u = 0; u < HH; ++u) {
            float ig = fmaf(sWx0[u],          xt, sB0[u]);
            float fg = fmaf(sWx0[HH + u],     xt, sB0[HH + u]);
            float gg = fmaf(sWx0[2 * HH + u], xt, sB0[2 * HH + u]);
            float og = fmaf(sWx0[3 * HH + u], xt, sB0[3 * HH + u]);
            #pragma unroll
            for (int q = 0; q < 4; ++q) {
                const vf4 wi = sW0[(u)          * 4 + q];
                const vf4 wf = sW0[(HH + u)     * 4 + q];
                const vf4 wg = sW0[(2 * HH + u) * 4 + q];
                const vf4 wo = sW0[(3 * HH + u) * 4 + q];
                #pragma unroll
                for (int j = 0; j < 4; ++j) {
                    const float hk = h1[q * 4 + j];
                    ig = fmaf(wi[j], hk, ig);
                    fg = fmaf(wf[j], hk, fg);
                    gg = fmaf(wg[j], hk, gg);
                    og = fmaf(wo[j], hk, og);
                }
            }
            const float cc = sigm2(fg) * c1[u] + sigm2(ig) * tanh2(gg);
            c1[u] = cc;
            h1n[u] = sigm2(og) * tanh2(2.0f * LOG2E * cc);
        }

        // ---------- layer 2 (input = h1n) ----------
        vf16 h2n;
        h2n[15] = 0.0f;
        #pragma unroll
        for (int u = 0; u < HH; ++u) {
            float ig = sB1[u];
            float fg = sB1[HH + u];
            float gg = sB1[2 * HH + u];
            float og = sB1[3 * HH + u];
            #pragma unroll
            for (int q = 0; q < 4; ++q) {
                const vf4 wi = sW1i[(u)          * 4 + q];
                const vf4 wf = sW1i[(HH + u)     * 4 + q];
                const vf4 wg = sW1i[(2 * HH + u) * 4 + q];
                const vf4 wo = sW1i[(3 * HH + u) * 4 + q];
                #pragma unroll
                for (int j = 0; j < 4; ++j) {
                    const float hk = h1n[q * 4 + j];
                    ig = fmaf(wi[j], hk, ig);
                    fg = fmaf(wf[j], hk, fg);
                    gg = fmaf(wg[j], hk, gg);
                    og = fmaf(wo[j], hk, og);
                }
            }
            #pragma unroll
            for (int q = 0; q < 4; ++q) {
                const vf4 wi = sW1h[(u)          * 4 + q];
                const vf4 wf = sW1h[(HH + u)     * 4 + q];
                const vf4 wg = sW1h[(2 * HH + u) * 4 + q];
                const vf4 wo = sW1h[(3 * HH + u) * 4 + q];
                #pragma unroll
                for (int j = 0; j < 4; ++j) {
                    const float hk = h2[q * 4 + j];
                    ig = fmaf(wi[j], hk, ig);
                    fg = fmaf(wf[j], hk, fg);
                    gg = fmaf(wg[j], hk, gg);
                    og = fmaf(wo[j], hk, og);
                }
            }
            const float cc = sigm2(fg) * c2[u] + sigm2(ig) * tanh2(gg);
            c2[u] = cc;
            h2n[u] = sigm2(og) * tanh2(2.0f * LOG2E * cc);
        }

        h1 = h1n;
        h2 = h2n;

        // feat[b,t] = h2_t[14]; accumulate collapsed head online
        acc = fmaf(h2n[HH - 1], sV[t], acc);
    }

    out[b] = acc;
}

extern "C" void kernel_launch(void* const* d_in, const int* in_sizes, int n_in,
                              void* d_out, int out_size, void* d_ws, size_t ws_size,
                              hipStream_t stream) {
    (void)n_in; (void)d_ws; (void)ws_size; (void)out_size;
    const float* x    = (const float*)d_in[0];
    const float* Wih0 = (const float*)d_in[1];
    const float* Whh0 = (const float*)d_in[2];
    const float* bih0 = (const float*)d_in[3];
    const float* bhh0 = (const float*)d_in[4];
    const float* Wih1 = (const float*)d_in[5];
    const float* Whh1 = (const float*)d_in[6];
    const float* bih1 = (const float*)d_in[7];
    const float* bhh1 = (const float*)d_in[8];
    const float* W1   = (const float*)d_in[9];
    const float* b1   = (const float*)d_in[10];
    const float* W2   = (const float*)d_in[11];
    const float* b2   = (const float*)d_in[12];
    const float* W3   = (const float*)d_in[13];
    const float* b3   = (const float*)d_in[14];
    float* out = (float*)d_out;

    const int B = in_sizes[0] / TT;   // 131072
    const int block = 256;
    const int grid = (B + block - 1) / block;

    lstm_fused<<<grid, block, 0, stream>>>(x, Wih0, Whh0, bih0, bhh0,
                                           Wih1, Whh1, bih1, bhh1,
                                           W1, b1, W2, b2, W3, b3, out, B);
}

// Round 5
// 573.634 us; speedup vs baseline: 8.7123x; 8.5173x over previous
//
#include <hip/hip_runtime.h>

// Problem constants: H1=15, H2=60, H3=20, T=15, IN=1
#define HH   15
#define TT   15
#define NH2  60
#define NH3  20

#define LOG2E  1.44269504088896340736f
#define NLOG2E (-1.44269504088896340736f)
#define L2E2   2.88538908177608681472f   // 2*LOG2E

__device__ __forceinline__ float fast_rcp(float x)  { return __builtin_amdgcn_rcpf(x); }
__device__ __forceinline__ float fast_exp2(float x) { return __builtin_amdgcn_exp2f(x); }
// NaN-safe: exp2 -> inf => rcp -> 0.
__device__ __forceinline__ float sigm(float x)  { return fast_rcp(1.0f + fast_exp2(NLOG2E * x)); }
__device__ __forceinline__ float tanhx(float x) { return 1.0f - 2.0f * fast_rcp(1.0f + fast_exp2(L2E2 * x)); }

// 15-term dot of weight row r of W (row-major [60][15]) with named scalars P##0..P##14.
// All indices compile-time constants -> wave-uniform s_load weight operands.
#define DOT15(W, r, P, init) \
  fmaf((W)[(r)*15+14], P##14, fmaf((W)[(r)*15+13], P##13, fmaf((W)[(r)*15+12], P##12, \
  fmaf((W)[(r)*15+11], P##11, fmaf((W)[(r)*15+10], P##10, fmaf((W)[(r)*15+9],  P##9,  \
  fmaf((W)[(r)*15+8],  P##8,  fmaf((W)[(r)*15+7],  P##7,  fmaf((W)[(r)*15+6],  P##6,  \
  fmaf((W)[(r)*15+5],  P##5,  fmaf((W)[(r)*15+4],  P##4,  fmaf((W)[(r)*15+3],  P##3,  \
  fmaf((W)[(r)*15+2],  P##2,  fmaf((W)[(r)*15+1],  P##1,  fmaf((W)[(r)*15+0],  P##0,  (init))))))))))))))))

#define S15(M) M(0) M(1) M(2) M(3) M(4) M(5) M(6) M(7) M(8) M(9) M(10) M(11) M(12) M(13) M(14)

// All per-thread state as NAMED SCALARS (trivially SSA; rounds 1-4 post-mortem:
// arrays AND ext-vectors with loop indices stayed in scratch -> 11.5 GB HBM).
#define DECL_STATE(u) float h1_##u = 0.0f, c1_##u = 0.0f, h2_##u = 0.0f, c2_##u = 0.0f;
#define DECL_NEXT(u)  float h1n_##u, h2n_##u;
#define COPY_STATE(u) h1_##u = h1n_##u; h2_##u = h2n_##u;

// Layer-1 unit u: 4 gate rows (u, 15+u, 30+u, 45+u) of Whh0; x-term + bias init.
#define L1U(u) { \
    const float4 b0 = sB0v[u]; const float4 wx = sWx0v[u]; \
    const float ig = DOT15(Whh0, (u),      h1_, fmaf(wx.x, xt, b0.x)); \
    const float fg = DOT15(Whh0, (15+(u)), h1_, fmaf(wx.y, xt, b0.y)); \
    const float gg = DOT15(Whh0, (30+(u)), h1_, fmaf(wx.z, xt, b0.z)); \
    const float og = DOT15(Whh0, (45+(u)), h1_, fmaf(wx.w, xt, b0.w)); \
    const float cc = sigm(fg) * c1_##u + sigm(ig) * tanhx(gg); \
    c1_##u = cc; \
    h1n_##u = sigm(og) * tanhx(cc); \
  }

// Layer-2 unit u: Wih1 row dot h1n (inner chain) then Whh1 row dot h2 (outer).
#define L2U(u) { \
    const float4 b1v = sB1v[u]; \
    const float ig = DOT15(Whh1, (u),      h2_, DOT15(Wih1, (u),      h1n_, b1v.x)); \
    const float fg = DOT15(Whh1, (15+(u)), h2_, DOT15(Wih1, (15+(u)), h1n_, b1v.y)); \
    const float gg = DOT15(Whh1, (30+(u)), h2_, DOT15(Wih1, (30+(u)), h1n_, b1v.z)); \
    const float og = DOT15(Whh1, (45+(u)), h2_, DOT15(Wih1, (45+(u)), h1n_, b1v.w)); \
    const float cc = sigm(fg) * c2_##u + sigm(ig) * tanhx(gg); \
    c2_##u = cc; \
    h2n_##u = sigm(og) * tanhx(cc); \
  }

__global__ __launch_bounds__(256, 2)
void lstm_fused(const float* __restrict__ x,
                const float* __restrict__ Wih0, const float* __restrict__ Whh0,
                const float* __restrict__ bih0, const float* __restrict__ bhh0,
                const float* __restrict__ Wih1, const float* __restrict__ Whh1,
                const float* __restrict__ bih1, const float* __restrict__ bhh1,
                const float* __restrict__ W1, const float* __restrict__ b1,
                const float* __restrict__ W2, const float* __restrict__ b2,
                const float* __restrict__ W3, const float* __restrict__ b3,
                float* __restrict__ out, int B)
{
    // Only biases (interleaved {i,f,g,o} float4 per unit -> one ds_read_b128),
    // Wih0 column, and the collapsed head live in LDS. Weight matrices are
    // read straight from global with constant indices (uniform -> s_load/K$).
    __shared__ float4 sB0v[HH];    // (bih0+bhh0) interleaved per unit
    __shared__ float4 sB1v[HH];    // (bih1+bhh1) interleaved per unit
    __shared__ float4 sWx0v[HH];   // Wih0 rows {u,15+u,30+u,45+u}
    __shared__ float  sV[TT];      // collapsed head vector
    __shared__ float  sU[NH2];     // temp: W3 @ W2
    __shared__ float  sCb;         // collapsed head bias

    const int tid = threadIdx.x;

    if (tid < HH) {
        sB0v[tid] = make_float4(bih0[tid]      + bhh0[tid],
                                bih0[15 + tid] + bhh0[15 + tid],
                                bih0[30 + tid] + bhh0[30 + tid],
                                bih0[45 + tid] + bhh0[45 + tid]);
        sB1v[tid] = make_float4(bih1[tid]      + bhh1[tid],
                                bih1[15 + tid] + bhh1[15 + tid],
                                bih1[30 + tid] + bhh1[30 + tid],
                                bih1[45 + tid] + bhh1[45 + tid]);
        sWx0v[tid] = make_float4(Wih0[tid], Wih0[15 + tid], Wih0[30 + tid], Wih0[45 + tid]);
    }
    // collapse the affine head: u = W3@W2 (60), v = u@W1 (15), c scalar
    if (tid < NH2) {
        float u = 0.0f;
        #pragma unroll
        for (int k = 0; k < NH3; ++k) u = fmaf(W3[k], W2[k * NH2 + tid], u);
        sU[tid] = u;
    }
    __syncthreads();
    if (tid < TT) {
        float v = 0.0f;
        for (int j = 0; j < NH2; ++j) v = fmaf(sU[j], W1[j * HH + tid], v);
        sV[tid] = v;
    }
    if (tid == 0) {
        float c = b3[0];
        for (int k = 0; k < NH3; ++k) c = fmaf(W3[k], b2[k], c);
        for (int j = 0; j < NH2; ++j) c = fmaf(sU[j], b1[j], c);
        sCb = c;
    }
    __syncthreads();

    const int b = blockIdx.x * 256 + tid;
    if (b >= B) return;

    const float* xp = x + (size_t)b * TT;

    S15(DECL_STATE)          // h1_0..14, c1_0..14, h2_0..14, c2_0..14 = 0

    float acc = sCb;

    #pragma unroll 1         // one step of code (~25 KB); 15x would blow L1I
    for (int t = 0; t < TT; ++t) {
        const float xt = xp[t];

        S15(DECL_NEXT)       // h1n_*, h2n_*

        S15(L1U)             // layer 1: 15 units, 4 gates each
        S15(L2U)             // layer 2: 15 units, 4 gates each
        S15(COPY_STATE)

        // feat[b,t] = h2_t[14]; accumulate collapsed head online
        acc = fmaf(h2n_14, sV[t], acc);
    }

    out[b] = acc;
}

extern "C" void kernel_launch(void* const* d_in, const int* in_sizes, int n_in,
                              void* d_out, int out_size, void* d_ws, size_t ws_size,
                              hipStream_t stream) {
    (void)n_in; (void)d_ws; (void)ws_size; (void)out_size;
    const float* x    = (const float*)d_in[0];
    const float* Wih0 = (const float*)d_in[1];
    const float* Whh0 = (const float*)d_in[2];
    const float* bih0 = (const float*)d_in[3];
    const float* bhh0 = (const float*)d_in[4];
    const float* Wih1 = (const float*)d_in[5];
    const float* Whh1 = (const float*)d_in[6];
    const float* bih1 = (const float*)d_in[7];
    const float* bhh1 = (const float*)d_in[8];
    const float* W1   = (const float*)d_in[9];
    const float* b1   = (const float*)d_in[10];
    const float* W2   = (const float*)d_in[11];
    const float* b2   = (const float*)d_in[12];
    const float* W3   = (const float*)d_in[13];
    const float* b3   = (const float*)d_in[14];
    float* out = (float*)d_out;

    const int B = in_sizes[0] / TT;   // 131072
    const int block = 256;
    const int grid = (B + block - 1) / block;

    lstm_fused<<<grid, block, 0, stream>>>(x, Wih0, Whh0, bih0, bhh0,
                                           Wih1, Whh1, bih1, bhh1,
                                           W1, b1, W2, b2, W3, b3, out, B);
}

// Round 6
// 347.580 us; speedup vs baseline: 14.3785x; 1.6504x over previous
//
#include <hip/hip_runtime.h>

// Problem constants: H1=15, H2=60, H3=20, T=15, IN=1
#define HH   15
#define TT   15
#define NH2  60
#define NH3  20

#define LOG2E  1.44269504088896340736f
#define L2E2   2.88539008177792680736f   // 2*LOG2E

// d_ws layout (float/u32 indices):
//   [0,480)    half2: Whh0 rows, 60 rows x 8 half2 (k-pairs, padded, gate-scaled)
//   [480,960)  half2: Wih1 rows
//   [960,1440) half2: Whh1 rows
//   [1440,1500) float4 x15: B0 per unit {i,f,g,o} = (bih0+bhh0)*scale
//   [1500,1560) float4 x15: B1 per unit
//   [1560,1620) float4 x15: WX per unit {Wih0 rows u,15+u,30+u,45+u}*scale
//   [1620,1635) float: collapsed head v[15]
//   [1635]      float: collapsed head bias
#define OFF_W0   0
#define OFF_W1I  480
#define OFF_W1H  960
#define OFF_B0   360     // in float4 units: 1440/4
#define OFF_B1   375
#define OFF_WX   390
#define OFF_V    1620
#define OFF_CB   1635

typedef _Float16 h2_t __attribute__((ext_vector_type(2)));

__device__ __forceinline__ float fast_rcp(float x)  { return __builtin_amdgcn_rcpf(x); }
__device__ __forceinline__ float fast_exp2(float x) { return __builtin_amdgcn_exp2f(x); }
// args pre-scaled by LOG2E (sigm) / 2*LOG2E (tanh). NaN-safe: exp2->inf => rcp->0.
__device__ __forceinline__ float sigm_s(float y) { return fast_rcp(1.0f + fast_exp2(-y)); }
__device__ __forceinline__ float tanh_s(float y) { return 1.0f - 2.0f * fast_rcp(1.0f + fast_exp2(y)); }
__device__ __forceinline__ float tanh_c(float c) { return tanh_s(L2E2 * c); }

#define FD(a, b, c) __builtin_amdgcn_fdot2((a), (b), (c), false)

// 16-wide (8 x half2-pair) dot of padded row r of W against packed state P##h0..P##h7,
// f32 accumulate chained from (init). Weight operand wave-uniform -> SGPR.
#define DOT8H(W, r, P, init) \
  FD((W)[(r)*8+7], P##h7, FD((W)[(r)*8+6], P##h6, FD((W)[(r)*8+5], P##h5, \
  FD((W)[(r)*8+4], P##h4, FD((W)[(r)*8+3], P##h3, FD((W)[(r)*8+2], P##h2, \
  FD((W)[(r)*8+1], P##h1, FD((W)[(r)*8+0], P##h0, (init)))))))))

#define S15(M) M(0) M(1) M(2) M(3) M(4) M(5) M(6) M(7) M(8) M(9) M(10) M(11) M(12) M(13) M(14)
#define P8(M)  M(0) M(1) M(2) M(3) M(4) M(5) M(6) M(7)

#define DECL_C(u)  float c1_##u = 0.0f, c2_##u = 0.0f;
#define DECL_HP(p) h2_t h1h##p = {(_Float16)0.f, (_Float16)0.f}, h2h##p = h1h##p;
#define DECL_N(u)  float h1n_##u, h2n_##u;
#define COPY_HP(p) h1h##p = h1nh##p; h2h##p = h2nh##p;

#define L1U(u) { \
    const float4 b0 = B0p[u]; const float4 wx = WXp[u]; \
    const float ig = DOT8H(W0p, (u),        h1, fmaf(wx.x, xt, b0.x)); \
    const float fg = DOT8H(W0p, (15+(u)),   h1, fmaf(wx.y, xt, b0.y)); \
    const float gg = DOT8H(W0p, (30+(u)),   h1, fmaf(wx.z, xt, b0.z)); \
    const float og = DOT8H(W0p, (45+(u)),   h1, fmaf(wx.w, xt, b0.w)); \
    const float cc = sigm_s(fg) * c1_##u + sigm_s(ig) * tanh_s(gg); \
    c1_##u = cc; \
    h1n_##u = sigm_s(og) * tanh_c(cc); \
  }

#define L2U(u) { \
    const float4 b1 = B1p[u]; \
    const float ig = DOT8H(W1hp, (u),      h2, DOT8H(W1ip, (u),      h1n, b1.x)); \
    const float fg = DOT8H(W1hp, (15+(u)), h2, DOT8H(W1ip, (15+(u)), h1n, b1.y)); \
    const float gg = DOT8H(W1hp, (30+(u)), h2, DOT8H(W1ip, (30+(u)), h1n, b1.z)); \
    const float og = DOT8H(W1hp, (45+(u)), h2, DOT8H(W1ip, (45+(u)), h1n, b1.w)); \
    const float cc = sigm_s(fg) * c2_##u + sigm_s(ig) * tanh_s(gg); \
    c2_##u = cc; \
    h2n_##u = sigm_s(og) * tanh_c(cc); \
  }

// ---- prep kernel: scale, pad, f16-pack weights into d_ws; collapse head ----
__global__ void lstm_prep(const float* __restrict__ Wih0, const float* __restrict__ Whh0,
                          const float* __restrict__ bih0, const float* __restrict__ bhh0,
                          const float* __restrict__ Wih1, const float* __restrict__ Whh1,
                          const float* __restrict__ bih1, const float* __restrict__ bhh1,
                          const float* __restrict__ W1, const float* __restrict__ b1,
                          const float* __restrict__ W2, const float* __restrict__ b2,
                          const float* __restrict__ W3, const float* __restrict__ b3,
                          float* __restrict__ wsf)
{
    const int tid = threadIdx.x;
    h2_t* wsh = (h2_t*)wsf;
    float4* wsf4 = (float4*)wsf;

    // weight rows: r in [0,60); gate g = r/15; scale 2*LOG2E for g-gate else LOG2E
    for (int i = tid; i < 480; i += 256) {
        const int r = i >> 3, p = i & 7;
        const float sc = (r >= 30 && r < 45) ? L2E2 : LOG2E;
        const int k0 = 2 * p, k1 = 2 * p + 1;
        {
            const float v0 = Whh0[r * 15 + k0] * sc;
            const float v1 = (k1 < 15) ? Whh0[r * 15 + k1] * sc : 0.0f;
            wsh[OFF_W0 + i] = h2_t{(_Float16)v0, (_Float16)v1};
        }
        {
            const float v0 = Wih1[r * 15 + k0] * sc;
            const float v1 = (k1 < 15) ? Wih1[r * 15 + k1] * sc : 0.0f;
            wsh[OFF_W1I + i] = h2_t{(_Float16)v0, (_Float16)v1};
        }
        {
            const float v0 = Whh1[r * 15 + k0] * sc;
            const float v1 = (k1 < 15) ? Whh1[r * 15 + k1] * sc : 0.0f;
            wsh[OFF_W1H + i] = h2_t{(_Float16)v0, (_Float16)v1};
        }
    }
    if (tid < HH) {
        wsf4[OFF_B0 + tid] = make_float4((bih0[tid]      + bhh0[tid])      * LOG2E,
                                         (bih0[15 + tid] + bhh0[15 + tid]) * LOG2E,
                                         (bih0[30 + tid] + bhh0[30 + tid]) * L2E2,
                                         (bih0[45 + tid] + bhh0[45 + tid]) * LOG2E);
        wsf4[OFF_B1 + tid] = make_float4((bih1[tid]      + bhh1[tid])      * LOG2E,
                                         (bih1[15 + tid] + bhh1[15 + tid]) * LOG2E,
                                         (bih1[30 + tid] + bhh1[30 + tid]) * L2E2,
                                         (bih1[45 + tid] + bhh1[45 + tid]) * LOG2E);
        wsf4[OFF_WX + tid] = make_float4(Wih0[tid] * LOG2E, Wih0[15 + tid] * LOG2E,
                                         Wih0[30 + tid] * L2E2, Wih0[45 + tid] * LOG2E);
    }
    // collapse affine head: u = W3@W2 (60), v = u@W1 (15), cb scalar
    __shared__ float sU[NH2];
    if (tid < NH2) {
        float u = 0.0f;
        #pragma unroll
        for (int k = 0; k < NH3; ++k) u = fmaf(W3[k], W2[k * NH2 + tid], u);
        sU[tid] = u;
    }
    __syncthreads();
    if (tid < TT) {
        float v = 0.0f;
        for (int j = 0; j < NH2; ++j) v = fmaf(sU[j], W1[j * HH + tid], v);
        wsf[OFF_V + tid] = v;
    }
    if (tid == 0) {
        float c = b3[0];
        for (int k = 0; k < NH3; ++k) c = fmaf(W3[k], b2[k], c);
        for (int j = 0; j < NH2; ++j) c = fmaf(sU[j], b1[j], c);
        wsf[OFF_CB] = c;
    }
}

// ---- main kernel: one thread per batch element; f16-pair dots, f32 accumulate ----
__global__ __launch_bounds__(256, 2)
void lstm_fused(const float* __restrict__ x,
                const float* __restrict__ wsf,
                float* __restrict__ out, int B)
{
    const h2_t*   W0p  = (const h2_t*)wsf + OFF_W0;
    const h2_t*   W1ip = (const h2_t*)wsf + OFF_W1I;
    const h2_t*   W1hp = (const h2_t*)wsf + OFF_W1H;
    const float4* B0p  = (const float4*)wsf + OFF_B0;
    const float4* B1p  = (const float4*)wsf + OFF_B1;
    const float4* WXp  = (const float4*)wsf + OFF_WX;
    const float*  Vp   = wsf + OFF_V;

    const int b = blockIdx.x * 256 + threadIdx.x;
    if (b >= B) return;

    const float* xp = x + (size_t)b * TT;

    S15(DECL_C)       // c1_*, c2_* f32 scalars
    P8(DECL_HP)       // h1h0..7, h2h0..7 packed f16 pairs (pair 7 .y stays 0)

    float acc = wsf[OFF_CB];

    #pragma unroll 1  // one step of code; keep body inside L1I
    for (int t = 0; t < TT; ++t) {
        const float xt = xp[t];

        S15(DECL_N)   // h1n_*, h2n_* f32 scalars

        S15(L1U)      // layer 1: 15 units x 4 gates, 8 dot2 each

        // pack h1n -> f16 pairs for layer-2 A-operand
        h2_t h1nh0 = {(_Float16)h1n_0,  (_Float16)h1n_1};
        h2_t h1nh1 = {(_Float16)h1n_2,  (_Float16)h1n_3};
        h2_t h1nh2 = {(_Float16)h1n_4,  (_Float16)h1n_5};
        h2_t h1nh3 = {(_Float16)h1n_6,  (_Float16)h1n_7};
        h2_t h1nh4 = {(_Float16)h1n_8,  (_Float16)h1n_9};
        h2_t h1nh5 = {(_Float16)h1n_10, (_Float16)h1n_11};
        h2_t h1nh6 = {(_Float16)h1n_12, (_Float16)h1n_13};
        h2_t h1nh7 = {(_Float16)h1n_14, (_Float16)0.f};

        S15(L2U)      // layer 2: 15 units x 4 gates, 16 dot2 each

        h2_t h2nh0 = {(_Float16)h2n_0,  (_Float16)h2n_1};
        h2_t h2nh1 = {(_Float16)h2n_2,  (_Float16)h2n_3};
        h2_t h2nh2 = {(_Float16)h2n_4,  (_Float16)h2n_5};
        h2_t h2nh3 = {(_Float16)h2n_6,  (_Float16)h2n_7};
        h2_t h2nh4 = {(_Float16)h2n_8,  (_Float16)h2n_9};
        h2_t h2nh5 = {(_Float16)h2n_10, (_Float16)h2n_11};
        h2_t h2nh6 = {(_Float16)h2n_12, (_Float16)h2n_13};
        h2_t h2nh7 = {(_Float16)h2n_14, (_Float16)0.f};

        P8(COPY_HP)   // h1h = h1nh; h2h = h2nh

        // feat[b,t] = h2_t[14]; accumulate collapsed head online (f32 path)
        acc = fmaf(h2n_14, Vp[t], acc);
    }

    out[b] = acc;
}

extern "C" void kernel_launch(void* const* d_in, const int* in_sizes, int n_in,
                              void* d_out, int out_size, void* d_ws, size_t ws_size,
                              hipStream_t stream) {
    (void)n_in; (void)ws_size; (void)out_size;
    const float* x    = (const float*)d_in[0];
    const float* Wih0 = (const float*)d_in[1];
    const float* Whh0 = (const float*)d_in[2];
    const float* bih0 = (const float*)d_in[3];
    const float* bhh0 = (const float*)d_in[4];
    const float* Wih1 = (const float*)d_in[5];
    const float* Whh1 = (const float*)d_in[6];
    const float* bih1 = (const float*)d_in[7];
    const float* bhh1 = (const float*)d_in[8];
    const float* W1   = (const float*)d_in[9];
    const float* b1   = (const float*)d_in[10];
    const float* W2   = (const float*)d_in[11];
    const float* b2   = (const float*)d_in[12];
    const float* W3   = (const float*)d_in[13];
    const float* b3   = (const float*)d_in[14];
    float* out = (float*)d_out;
    float* wsf = (float*)d_ws;

    const int B = in_sizes[0] / TT;   // 131072

    lstm_prep<<<1, 256, 0, stream>>>(Wih0, Whh0, bih0, bhh0,
                                     Wih1, Whh1, bih1, bhh1,
                                     W1, b1, W2, b2, W3, b3, wsf);

    lstm_fused<<<(B + 255) / 256, 256, 0, stream>>>(x, wsf, out, B);
}

// Round 7
// 144.822 us; speedup vs baseline: 34.5091x; 2.4000x over previous
//
#include <hip/hip_runtime.h>

// Problem constants: H1=15, H2=60, H3=20, T=15, IN=1
#define HH   15
#define TT   15
#define NH2  60
#define NH3  20

#define LOG2E 1.44269504088896340736f
#define L2E2  2.88539008177792680736f   // 2*LOG2E

typedef _Float16 f16x8 __attribute__((ext_vector_type(8)));
typedef float    f32x4 __attribute__((ext_vector_type(4)));

// ws layout (dwords):
//   frag f in 0..7: dwords [f*256 + lane*4 + d]   (B-fragments, f16 pairs)
//   v[15] at 2048..2062 ; cb at 2063
#define WS_V  2048
#define WS_CB 2063

__device__ __forceinline__ float fast_rcp(float x)  { return __builtin_amdgcn_rcpf(x); }
__device__ __forceinline__ float fast_exp2(float x) { return __builtin_amdgcn_exp2f(x); }
// args pre-scaled by LOG2E (sigm) / 2*LOG2E (tanh); NaN-safe (exp2->inf => rcp->0)
__device__ __forceinline__ float sigm_s(float y) { return fast_rcp(1.0f + fast_exp2(-y)); }
__device__ __forceinline__ float tanh_s(float y) { return 1.0f - 2.0f * fast_rcp(1.0f + fast_exp2(y)); }

// ---------------- prep: pack B-fragments for v_mfma_f32_16x16x32_f16 ----------------
// B-frag layout: lane l holds B[k=(l>>4)*8+j][col=l&15], j=0..7, packed as 4 dwords.
// Tiles (N=16 cols): col c = unit u (u==15 pad); tile n in {0,1,2,3} = {i,f,g,o} gates,
// weight row r = n*15+u. K layout:
//   L1 (frags 0-3): k<15: Whh0[r][k] ; k==15: Wih0[r] (x slot) ; k==16: bias0[r] ; else 0
//   L2 (frags 4-7): k<15: Wih1[r][k] ; k==15: bias1[r] (A=1)   ; k in 16..30: Whh1[r][k-16] ; k==31: 0
// All values scaled by LOG2E (2*LOG2E for the g-gate tile n==2).
__global__ void lstm_prep(const float* __restrict__ Wih0, const float* __restrict__ Whh0,
                          const float* __restrict__ bih0, const float* __restrict__ bhh0,
                          const float* __restrict__ Wih1, const float* __restrict__ Whh1,
                          const float* __restrict__ bih1, const float* __restrict__ bhh1,
                          const float* __restrict__ W1, const float* __restrict__ b1,
                          const float* __restrict__ W2, const float* __restrict__ b2,
                          const float* __restrict__ W3, const float* __restrict__ b3,
                          float* __restrict__ wsf)
{
    const int tid = threadIdx.x;
    unsigned* wsu = (unsigned*)wsf;

    {   // one thread per (frag, lane)
        const int f = tid >> 6, l = tid & 63;
        const int n = f & 3;
        const bool isL2 = (f >= 4);
        const int u = l & 15, g = l >> 4;
        const float sc = (n == 2) ? L2E2 : LOG2E;
        const int r = n * 15 + u;
        float vals[8];
        #pragma unroll
        for (int j = 0; j < 8; ++j) {
            const int k = g * 8 + j;
            float v = 0.0f;
            if (u < 15) {
                if (!isL2) {
                    if (k < 15)       v = Whh0[r * 15 + k];
                    else if (k == 15) v = Wih0[r];
                    else if (k == 16) v = bih0[r] + bhh0[r];
                } else {
                    if (k < 15)       v = Wih1[r * 15 + k];
                    else if (k == 15) v = bih1[r] + bhh1[r];
                    else if (k < 31)  v = Whh1[r * 15 + (k - 16)];
                }
            }
            vals[j] = v * sc;
        }
        #pragma unroll
        for (int d = 0; d < 4; ++d) {
            union { _Float16 h[2]; unsigned u32; } p;
            p.h[0] = (_Float16)vals[2 * d];
            p.h[1] = (_Float16)vals[2 * d + 1];
            wsu[f * 256 + l * 4 + d] = p.u32;
        }
    }

    // collapsed affine head: u = W3@W2 (60), v = u@W1 (15), cb scalar
    __shared__ float sU[NH2];
    if (tid < NH2) {
        float ua = 0.0f;
        #pragma unroll
        for (int k = 0; k < NH3; ++k) ua = fmaf(W3[k], W2[k * NH2 + tid], ua);
        sU[tid] = ua;
    }
    __syncthreads();
    if (tid < TT) {
        float v = 0.0f;
        for (int j = 0; j < NH2; ++j) v = fmaf(sU[j], W1[j * HH + tid], v);
        wsf[WS_V + tid] = v;
    }
    if (tid == 0) {
        float c = b3[0];
        for (int k = 0; k < NH3; ++k) c = fmaf(W3[k], b2[k], c);
        for (int j = 0; j < NH2; ++j) c = fmaf(sU[j], b1[j], c);
        wsf[WS_CB] = c;
    }
}

// ---------------- main: 16 batch rows per wave, MFMA gates, lane-local cell update ----------------
// A-frag: lane l holds A[row=l&15][k=(l>>4)*8+j] -> ds_read_b128 from [16][32] f16 LDS buffer.
// D-frag: lane l holds D[row=(l>>4)*4+i][col=l&15] -> i/f/g/o of (row,unit=l&15) all in-lane.
__global__ __launch_bounds__(256)
__attribute__((amdgpu_waves_per_eu(4)))
void lstm_mfma(const float* __restrict__ x, const float* __restrict__ wsf,
               float* __restrict__ out, int B)
{
    const int tid = threadIdx.x;
    const int wid = tid >> 6;
    const int l   = tid & 63;
    const int u   = l & 15;     // A-row / D-col (unit)
    const int g   = l >> 4;
    const int wbase = (blockIdx.x * 4 + wid) * 16;   // batch row base for this wave

    // per-wave A-staging buffers: [0]=L1 A rows, [1]=L2 A rows (wave-private, no barriers)
    __shared__ __align__(16) _Float16 lds[4][2][16][32];

    // zero both buffers (1024 f16 = 512 dwords per wave)
    unsigned* ldsw = (unsigned*)&lds[wid][0][0][0];
    #pragma unroll
    for (int i = 0; i < 8; ++i) ldsw[l + 64 * i] = 0u;
    // constant slots: L1 bias multiplicand A[.][16]=1.0 ; L2 bias multiplicand A[.][15]=1.0
    if (l < 16) {
        lds[wid][0][l][16] = (_Float16)1.0f;
        lds[wid][1][l][15] = (_Float16)1.0f;
    }

    // preload the 8 B-fragments into registers (kept for the whole kernel)
    const uint4* wsq = (const uint4*)wsf;
    union FU { uint4 q; f16x8 h; };
#define LOADB(name, fidx) f16x8 name; { FU t_; t_.q = wsq[(fidx) * 64 + l]; name = t_.h; }
    LOADB(B0, 0) LOADB(B1, 1) LOADB(B2, 2) LOADB(B3, 3)
    LOADB(B4, 4) LOADB(B5, 5) LOADB(B6, 6) LOADB(B7, 7)
#undef LOADB

    const float cb = wsf[WS_CB];
    f32x4 acc = {cb, cb, cb, cb};
    f32x4 c1  = {0.0f, 0.0f, 0.0f, 0.0f};
    f32x4 c2  = {0.0f, 0.0f, 0.0f, 0.0f};
    const f32x4 zc = {0.0f, 0.0f, 0.0f, 0.0f};

    const float* xrow = x + (size_t)(wbase + u) * TT;   // dereferenced only when l<16

#define MFMA(a, b, c) __builtin_amdgcn_mfma_f32_16x16x32_f16((a), (b), (c), 0, 0, 0)

    #pragma unroll 1
    for (int t = 0; t < TT; ++t) {
        // x slot for this step (rows 0..15); overwrites last step's pad-col h1n writes
        if (l < 16) lds[wid][0][l][15] = (_Float16)xrow[t];

        // ---- layer 1: G1 = [h1 | x | 1 | 0] @ B(L1) ----
        const f16x8 a1 = *(const f16x8*)&lds[wid][0][u][g * 8];
        f32x4 d0 = MFMA(a1, B0, zc);
        f32x4 d1 = MFMA(a1, B1, zc);
        f32x4 d2 = MFMA(a1, B2, zc);
        f32x4 d3 = MFMA(a1, B3, zc);

        // lane-local cell update; write h1n to both A-buffers (f16)
        // u==15 pad col: gates=0 -> h=0; [.][15] of buf0 is the x slot (rewritten next
        // step, safe) but buf1's [.][15] holds the bias 1.0 -> guard that write.
#define UPD1(i) { \
        const float si = sigm_s(d0[i]); \
        const float sf = sigm_s(d1[i]); \
        const float tg = tanh_s(d2[i]); \
        const float so = sigm_s(d3[i]); \
        const float cc = fmaf(si, tg, sf * c1[i]); \
        c1[i] = cc; \
        const float hh = so * tanh_s(L2E2 * cc); \
        const _Float16 hf = (_Float16)hh; \
        lds[wid][0][4 * g + (i)][u] = hf; \
        if (u < 15) lds[wid][1][4 * g + (i)][u] = hf; }
        UPD1(0) UPD1(1) UPD1(2) UPD1(3)
#undef UPD1

        // ---- layer 2: G2 = [h1n | 1 | h2_old | 0] @ B(L2) ----
        const f16x8 a2 = *(const f16x8*)&lds[wid][1][u][g * 8];
        d0 = MFMA(a2, B4, zc);
        d1 = MFMA(a2, B5, zc);
        d2 = MFMA(a2, B6, zc);
        d3 = MFMA(a2, B7, zc);

        const float vt = wsf[WS_V + t];   // uniform s_load
#define UPD2(i) { \
        const float si = sigm_s(d0[i]); \
        const float sf = sigm_s(d1[i]); \
        const float tg = tanh_s(d2[i]); \
        const float so = sigm_s(d3[i]); \
        const float cc = fmaf(si, tg, sf * c2[i]); \
        c2[i] = cc; \
        const float hh = so * tanh_s(L2E2 * cc); \
        lds[wid][1][4 * g + (i)][16 + u] = (_Float16)hh; \
        acc[i] = fmaf(hh, vt, acc[i]); }
        UPD2(0) UPD2(1) UPD2(2) UPD2(3)
#undef UPD2
    }
#undef MFMA

    // feat = h2[:, :, 14]: unit-14 lanes hold rows 4g..4g+3
    if (u == 14) {
        out[wbase + 4 * g + 0] = acc[0];
        out[wbase + 4 * g + 1] = acc[1];
        out[wbase + 4 * g + 2] = acc[2];
        out[wbase + 4 * g + 3] = acc[3];
    }
}

extern "C" void kernel_launch(void* const* d_in, const int* in_sizes, int n_in,
                              void* d_out, int out_size, void* d_ws, size_t ws_size,
                              hipStream_t stream) {
    (void)n_in; (void)ws_size; (void)out_size;
    const float* x    = (const float*)d_in[0];
    const float* Wih0 = (const float*)d_in[1];
    const float* Whh0 = (const float*)d_in[2];
    const float* bih0 = (const float*)d_in[3];
    const float* bhh0 = (const float*)d_in[4];
    const float* Wih1 = (const float*)d_in[5];
    const float* Whh1 = (const float*)d_in[6];
    const float* bih1 = (const float*)d_in[7];
    const float* bhh1 = (const float*)d_in[8];
    const float* W1   = (const float*)d_in[9];
    const float* b1   = (const float*)d_in[10];
    const float* W2   = (const float*)d_in[11];
    const float* b2   = (const float*)d_in[12];
    const float* W3   = (const float*)d_in[13];
    const float* b3   = (const float*)d_in[14];
    float* out = (float*)d_out;
    float* wsf = (float*)d_ws;

    const int B = in_sizes[0] / TT;   // 131072

    lstm_prep<<<1, 512, 0, stream>>>(Wih0, Whh0, bih0, bhh0,
                                     Wih1, Whh1, bih1, bhh1,
                                     W1, b1, W2, b2, W3, b3, wsf);

    // 16 batch rows per wave, 4 waves per block
    const int grid = B / (16 * 4);    // 2048
    lstm_mfma<<<grid, 256, 0, stream>>>(x, wsf, out, B);
}